// Round 4
// baseline (26.339 us; speedup 1.0000x reference)
//
#include <hip/hip_runtime.h>
#include <math.h>

#define NN 4096
#define MAGICV 0x5EED1234u

__device__ __forceinline__ void rot(float& r, float& i, float a, float sc) {
    float sn, cs;
    __sincosf(a, &sn, &cs);
    sn *= sc; cs *= sc;
    float nr = r * cs - i * sn;
    float ni = r * sn + i * cs;
    r = nr; i = ni;
}

// butterfly on a lane-index bit: new = mine + i * partner  (1/sqrt2 folded into rots)
__device__ __forceinline__ void stage_shfl(float& r0, float& i0, float& r1, float& i1, int mask) {
    float pr0 = __shfl_xor(r0, mask);
    float pi0 = __shfl_xor(i0, mask);
    float pr1 = __shfl_xor(r1, mask);
    float pi1 = __shfl_xor(i1, mask);
    r0 -= pi0; i0 += pr0;
    r1 -= pi1; i1 += pr1;
}

// butterfly on element-bit 0 (the two register-resident complexes)
__device__ __forceinline__ void stage_reg(float& r0, float& i0, float& r1, float& i1) {
    float nr0 = r0 - i1, ni0 = i0 + r1;
    float nr1 = r1 - i0, ni1 = i1 + r0;
    r0 = nr0; i0 = ni0; r1 = nr1; i1 = ni1;
}

__device__ __forceinline__ void b6(float& r0, float& i0, float& r1, float& i1) {
    stage_reg(r0, i0, r1, i1);
    stage_shfl(r0, i0, r1, i1, 1);
    stage_shfl(r0, i0, r1, i1, 2);
    stage_shfl(r0, i0, r1, i1, 4);
    stage_shfl(r0, i0, r1, i1, 8);
    stage_shfl(r0, i0, r1, i1, 16);
}

// Fused single-launch kernel: block i = (b = i>>2, c = i&3).
// Phase A: lo-chain (qubits 6..11) on rows h in [16c,16c+16), write Z[b][e][h], flag.
// Phase B: wait for b's 4 flags, hi-chain (qubits 0..5) on rows e in [16c,16c+16), write out.
__global__ __launch_bounds__(512) void fused_kernel(
    const float* __restrict__ x,
    const float* __restrict__ al, const float* __restrict__ be,
    const float* __restrict__ th, const float* __restrict__ ph,
    float* __restrict__ out, float2* __restrict__ Z, unsigned int* __restrict__ flags)
{
    __shared__ float2 tileA[64 * 17];            // phase A transpose: [e][hl], stride 17
    __shared__ float  tileB[2][64 * 17];         // phase B transpose: [h][el], stride 17

    const int t    = threadIdx.x;
    const int lane = t & 63;
    const int w    = t >> 6;          // wave 0..7
    const int half = lane >> 5;
    const int li   = lane & 31;
    const int b    = blockIdx.x >> 2;
    const int c    = blockIdx.x & 3;
    const int hl   = 2 * w + half;    // local row index 0..15

    // ================= phase A (lo axis, qubits 6..11) =================
    {
        const float* base = x + (size_t)b * 2 * NN;
        float2 vre = *(const float2*)(base + (c * 16 + 2 * w) * 64 + 2 * lane);
        float2 vim = *(const float2*)(base + NN + (c * 16 + 2 * w) * 64 + 2 * lane);
        float r0 = vre.x, i0 = vim.x;   // element e0 = 2*li of row h = 16c+hl
        float r1 = vre.y, i1 = vim.y;   // element e0+1

        // angles: bit m (1..5) of e = bit (m-1) of li ; qubit = 11 - m. bit0 <-> qubit 11.
        float aS = 0.f, tS = 0.f, pS = 0.f;
        #pragma unroll
        for (int m = 1; m <= 5; ++m) {
            int bit = (li >> (m - 1)) & 1;
            int q = 11 - m;
            aS += bit ? be[q] : al[q];
            if (!bit) { tS += th[q]; pS += ph[q]; }
        }
        float a0 = aS + al[11], a1 = aS + be[11];
        float t0 = tS + th[11], t1 = tS;
        float p0 = pS + ph[11], p1 = pS;

        rot(r0, i0, a0, 1.f); rot(r1, i1, a1, 1.f);
        b6(r0, i0, r1, i1);
        rot(r0, i0, t0, 0.125f); rot(r1, i1, t1, 0.125f);
        b6(r0, i0, r1, i1);
        rot(r0, i0, p0, 0.125f); rot(r1, i1, p1, 0.125f);

        // LDS transpose [e][hl] then coalesced Z write (float4 over h-chunk)
        int e0 = 2 * li;
        tileA[e0 * 17 + hl]       = make_float2(r0, i0);
        tileA[(e0 + 1) * 17 + hl] = make_float2(r1, i1);
        __syncthreads();
        int e = t >> 3, dh = (t & 7) * 2;
        float2 za = tileA[e * 17 + dh];
        float2 zb = tileA[e * 17 + dh + 1];
        float4 zv = make_float4(za.x, za.y, zb.x, zb.y);
        *(float4*)&Z[((size_t)b * 64 + e) * 64 + c * 16 + dh] = zv;
    }

    // ============ producer flag (release) + consumer wait (acquire) ============
    __syncthreads();   // all Z stores of this block complete (vmcnt drained per-wave)
    if (t == 0) {
        __threadfence();
        __hip_atomic_store(&flags[blockIdx.x], MAGICV, __ATOMIC_RELEASE, __HIP_MEMORY_SCOPE_AGENT);
    }
    if (t < 4) {
        while (__hip_atomic_load(&flags[b * 4 + t], __ATOMIC_ACQUIRE, __HIP_MEMORY_SCOPE_AGENT) != MAGICV) {
            __builtin_amdgcn_s_sleep(2);
        }
    }
    __syncthreads();

    // ================= phase B (hi axis, qubits 0..5) =================
    {
        float4 zv = *(const float4*)&Z[((size_t)b * 64 + c * 16 + 2 * w) * 64 + 2 * lane];
        float r0 = zv.x, i0 = zv.y;     // h0 = 2*li of row e = 16c+hl
        float r1 = zv.z, i1 = zv.w;     // h0+1

        // angles: bit m (1..5) of h = bit (m-1) of li ; qubit = 5 - m. bit0 <-> qubit 5.
        float aS = 0.f, tS = 0.f, pS = 0.f;
        #pragma unroll
        for (int m = 1; m <= 5; ++m) {
            int bit = (li >> (m - 1)) & 1;
            int q = 5 - m;
            aS += bit ? be[q] : al[q];
            if (!bit) { tS += th[q]; pS += ph[q]; }
        }
        float a0 = aS + al[5], a1 = aS + be[5];
        float t0 = tS + th[5], t1 = tS;
        float p0 = pS + ph[5], p1 = pS;

        rot(r0, i0, a0, 1.f); rot(r1, i1, a1, 1.f);
        b6(r0, i0, r1, i1);
        rot(r0, i0, t0, 0.125f); rot(r1, i1, t1, 0.125f);
        b6(r0, i0, r1, i1);
        rot(r0, i0, p0, 0.125f); rot(r1, i1, p1, 0.125f);

        // LDS transpose [h][el] then semi-coalesced out writes (float2 over e)
        int h0 = 2 * li, el = hl;
        tileB[0][h0 * 17 + el] = r0; tileB[0][(h0 + 1) * 17 + el] = r1;
        tileB[1][h0 * 17 + el] = i0; tileB[1][(h0 + 1) * 17 + el] = i1;
        __syncthreads();
        int h = t >> 3, de = (t & 7) * 2;
        float xr0 = tileB[0][h * 17 + de], xr1 = tileB[0][h * 17 + de + 1];
        float xi0 = tileB[1][h * 17 + de], xi1 = tileB[1][h * 17 + de + 1];
        float* outb = out + (size_t)b * 2 * NN;
        *(float2*)&outb[h * 64 + c * 16 + de]      = make_float2(xr0, xr1);
        *(float2*)&outb[NN + h * 64 + c * 16 + de] = make_float2(xi0, xi1);
    }
}

// ---------------- fallback (round-2 kernel) if ws too small ----------------
#define BLK 512
#define EPT 8
#define EXSZ (NN + (NN >> 5))

__device__ __forceinline__ void cmul(float& ar, float& ai, float br, float bi) {
    float nr = ar * br - ai * bi;
    float ni = ar * bi + ai * br;
    ar = nr; ai = ni;
}
__device__ __forceinline__ void bfly_pair(float* vr, float* vi, int a, int b) {
    float ur = vr[a], ui = vi[a], wr = vr[b], wi = vi[b];
    vr[a] = ur - wi; vi[a] = ui + wr;
    vr[b] = wr - ui; vi[b] = wi + ur;
}
__device__ __forceinline__ void bfly3(float* vr, float* vi) {
    bfly_pair(vr, vi, 0, 1); bfly_pair(vr, vi, 2, 3); bfly_pair(vr, vi, 4, 5); bfly_pair(vr, vi, 6, 7);
    bfly_pair(vr, vi, 0, 2); bfly_pair(vr, vi, 1, 3); bfly_pair(vr, vi, 4, 6); bfly_pair(vr, vi, 5, 7);
    bfly_pair(vr, vi, 0, 4); bfly_pair(vr, vi, 1, 5); bfly_pair(vr, vi, 2, 6); bfly_pair(vr, vi, 3, 7);
}
template<int PC, int PN>
__device__ __forceinline__ void exchange(float2* ex, float* vr, float* vi, int t) {
    const int basec = ((t >> PC) << (PC + 3)) | (t & ((1 << PC) - 1));
    #pragma unroll
    for (int r = 0; r < EPT; ++r) { int j = basec + (r << PC); ex[j + (j >> 5)] = make_float2(vr[r], vi[r]); }
    __syncthreads();
    const int basen = ((t >> PN) << (PN + 3)) | (t & ((1 << PN) - 1));
    #pragma unroll
    for (int r = 0; r < EPT; ++r) { int j = basen + (r << PN); float2 v = ex[j + (j >> 5)]; vr[r] = v.x; vi[r] = v.y; }
}
__global__ __launch_bounds__(BLK) void qubit_layer_fb(
    const float* __restrict__ x, const float* __restrict__ alphas, const float* __restrict__ betas,
    const float* __restrict__ thetas, const float* __restrict__ phis, float* __restrict__ out)
{
    __shared__ float2 ex0[EXSZ];
    __shared__ float2 ex1[EXSZ];
    __shared__ float2 tbl[6][64];
    const int b = blockIdx.x;
    const int t = threadIdx.x;
    if (t < 384) {
        int part = t >> 6, idx = t & 63, set = part >> 1, half = part & 1;
        float a = 0.f;
        #pragma unroll
        for (int m = 0; m < 6; ++m) {
            int q = half ? m : (6 + m);
            int bit = (idx >> (5 - m)) & 1;
            float av, bv;
            if (set == 0)      { av = alphas[q]; bv = betas[q]; }
            else if (set == 1) { av = thetas[q]; bv = 0.f; }
            else               { av = phis[q];   bv = 0.f; }
            a += bit ? bv : av;
        }
        float s, c2; __sincosf(a, &s, &c2);
        float sc = (set >= 1 && half == 0) ? (1.0f / 64.0f) : 1.0f;
        tbl[part][idx] = make_float2(c2 * sc, s * sc);
    }
    float vr[EPT], vi[EPT];
    const float* xr = x + (size_t)b * 2 * NN;
    const float* xi = xr + NN;
    {
        float4 a0 = ((const float4*)(xr + t * EPT))[0];
        float4 a1 = ((const float4*)(xr + t * EPT))[1];
        float4 c0 = ((const float4*)(xi + t * EPT))[0];
        float4 c1 = ((const float4*)(xi + t * EPT))[1];
        vr[0]=a0.x; vr[1]=a0.y; vr[2]=a0.z; vr[3]=a0.w; vr[4]=a1.x; vr[5]=a1.y; vr[6]=a1.z; vr[7]=a1.w;
        vi[0]=c0.x; vi[1]=c0.y; vi[2]=c0.z; vi[3]=c0.w; vi[4]=c1.x; vi[5]=c1.y; vi[6]=c1.z; vi[7]=c1.w;
    }
    __syncthreads();
    {
        float2 eh = tbl[1][t >> 3];
        #pragma unroll
        for (int r = 0; r < EPT; ++r) {
            float2 el = tbl[0][((t & 7) << 3) + r];
            float er = el.x, ei = el.y;
            cmul(er, ei, eh.x, eh.y);
            cmul(vr[r], vi[r], er, ei);
        }
    }
    bfly3(vr, vi);
    exchange<0, 3>(ex0, vr, vi, t); bfly3(vr, vi);
    exchange<3, 6>(ex1, vr, vi, t); bfly3(vr, vi);
    exchange<6, 9>(ex0, vr, vi, t); bfly3(vr, vi);
    {
        float2 el = tbl[2][t & 63];
        #pragma unroll
        for (int r = 0; r < EPT; ++r) {
            float2 eh = tbl[3][(t >> 6) + (r << 3)];
            float er = el.x, ei = el.y;
            cmul(er, ei, eh.x, eh.y);
            cmul(vr[r], vi[r], er, ei);
        }
    }
    exchange<9, 0>(ex1, vr, vi, t); bfly3(vr, vi);
    exchange<0, 3>(ex0, vr, vi, t); bfly3(vr, vi);
    exchange<3, 6>(ex1, vr, vi, t); bfly3(vr, vi);
    exchange<6, 9>(ex0, vr, vi, t); bfly3(vr, vi);
    float* outr = out + (size_t)b * 2 * NN;
    float* outi = outr + NN;
    {
        float2 el = tbl[4][t & 63];
        #pragma unroll
        for (int r = 0; r < EPT; ++r) {
            float2 eh = tbl[5][(t >> 6) + (r << 3)];
            float er = el.x, ei = el.y;
            cmul(er, ei, eh.x, eh.y);
            cmul(vr[r], vi[r], er, ei);
            outr[t + (r << 9)] = vr[r];
            outi[t + (r << 9)] = vi[r];
        }
    }
}

extern "C" void kernel_launch(void* const* d_in, const int* in_sizes, int n_in,
                              void* d_out, int out_size, void* d_ws, size_t ws_size,
                              hipStream_t stream) {
    const float* x      = (const float*)d_in[0];
    const float* alphas = (const float*)d_in[1];
    const float* betas  = (const float*)d_in[2];
    const float* thetas = (const float*)d_in[3];
    const float* phis   = (const float*)d_in[4];
    float* out = (float*)d_out;
    const int batch = in_sizes[0] / (2 * NN);          // 64

    const size_t zbytes = (size_t)batch * 64 * 64 * sizeof(float2);   // 2 MB
    const size_t need   = zbytes + (size_t)batch * 4 * sizeof(unsigned int);
    if (ws_size >= need) {
        float2* Z = (float2*)d_ws;
        unsigned int* flags = (unsigned int*)((char*)d_ws + zbytes);
        fused_kernel<<<batch * 4, 512, 0, stream>>>(x, alphas, betas, thetas, phis, out, Z, flags);
    } else {
        qubit_layer_fb<<<batch, BLK, 0, stream>>>(x, alphas, betas, thetas, phis, out);
    }
}

// Round 5
// 15.374 us; speedup vs baseline: 1.7131x; 1.7131x over previous
//
#include <hip/hip_runtime.h>
#include <math.h>

#define NN 4096
#define BLK 512
#define EPT 8
#define PADSZ (NN + (NN >> 3))   // 4608 complexes, padded idx jj = j + (j>>3)

__device__ __forceinline__ void rot(float& r, float& i, float a, float sc) {
    float sn, cs;
    __sincosf(a, &sn, &cs);
    sn *= sc; cs *= sc;
    float nr = r * cs - i * sn;
    float ni = r * sn + i * cs;
    r = nr; i = ni;
}

// new_u = u + i*w ; new_w = w + i*u  (1/sqrt2 folded into theta/phi rotations)
__device__ __forceinline__ void bfly_pair(float* vr, float* vi, int a, int b) {
    float ur = vr[a], ui = vi[a], wr = vr[b], wi = vi[b];
    vr[a] = ur - wi; vi[a] = ui + wr;
    vr[b] = wr - ui; vi[b] = wi + ur;
}

// butterflies on the 3 register-resident bits
__device__ __forceinline__ void bfly3(float* vr, float* vi) {
    bfly_pair(vr, vi, 0, 1); bfly_pair(vr, vi, 2, 3); bfly_pair(vr, vi, 4, 5); bfly_pair(vr, vi, 6, 7);
    bfly_pair(vr, vi, 0, 2); bfly_pair(vr, vi, 1, 3); bfly_pair(vr, vi, 4, 6); bfly_pair(vr, vi, 5, 7);
    bfly_pair(vr, vi, 0, 4); bfly_pair(vr, vi, 1, 5); bfly_pair(vr, vi, 2, 6); bfly_pair(vr, vi, 3, 7);
}

// element index held by (t, r) at layout P (register-resident bits P..P+2)
template<int P>
__device__ __forceinline__ int jidx(int t, int r) {
    return ((t >> P) << (P + 3)) | (r << P) | (t & ((1 << P) - 1));
}

// Exchange register-bit block PC -> PN through LDS.
// CROSS=false: transition keeps wave-owner bits (j[9:11]) -> wave-private slice,
// DS in-order per wave makes it safe with just a compiler fence.
template<int PC, int PN, bool CROSS>
__device__ __forceinline__ void exchange(float2* buf, float* vr, float* vi, int t) {
    #pragma unroll
    for (int r = 0; r < EPT; ++r) {
        int j = jidx<PC>(t, r);
        buf[j + (j >> 3)] = make_float2(vr[r], vi[r]);
    }
    if (CROSS) { __syncthreads(); }
    else       { asm volatile("" ::: "memory"); }
    #pragma unroll
    for (int r = 0; r < EPT; ++r) {
        int j = jidx<PN>(t, r);
        float2 v = buf[j + (j >> 3)];
        vr[r] = v.x; vi[r] = v.y;
    }
}

__global__ __launch_bounds__(BLK) void qubit_layer_kernel(
    const float* __restrict__ x,
    const float* __restrict__ al, const float* __restrict__ be,
    const float* __restrict__ th, const float* __restrict__ ph,
    float* __restrict__ out)
{
    __shared__ float2 B1[PADSZ];
    __shared__ float2 B2[PADSZ];

    const int t = threadIdx.x;
    const int b = blockIdx.x;

    // ---- load at p0 layout: j = t*8 + r ----
    const float* xr = x + (size_t)b * 2 * NN;
    const float* xi = xr + NN;
    float vr[EPT], vi[EPT];
    {
        float4 a0 = ((const float4*)(xr + t * EPT))[0];
        float4 a1 = ((const float4*)(xr + t * EPT))[1];
        float4 c0 = ((const float4*)(xi + t * EPT))[0];
        float4 c1 = ((const float4*)(xi + t * EPT))[1];
        vr[0]=a0.x; vr[1]=a0.y; vr[2]=a0.z; vr[3]=a0.w; vr[4]=a1.x; vr[5]=a1.y; vr[6]=a1.z; vr[7]=a1.w;
        vi[0]=c0.x; vi[1]=c0.y; vi[2]=c0.z; vi[3]=c0.w; vi[4]=c1.x; vi[5]=c1.y; vi[6]=c1.z; vi[7]=c1.w;
    }

    // ---- per-thread (lane-part) angle sums ----
    // p0: qubit q in [0..8] <-> t bit (8-q).  p9: qubit q in [3..11] <-> t bit (11-q).
    float Sin = 0.f, Sth = 0.f, Sph = 0.f;
    #pragma unroll
    for (int q = 0; q <= 8; ++q) {
        int bit = (t >> (8 - q)) & 1;
        Sin += bit ? be[q] : al[q];
        Sph += bit ? 0.f : ph[q];
    }
    #pragma unroll
    for (int q = 3; q <= 11; ++q) {
        int bit = (t >> (11 - q)) & 1;
        Sth += bit ? 0.f : th[q];
    }

    // ---- D_in at p0: qubits 9,10,11 <-> r bits 2,1,0 ----
    #pragma unroll
    for (int r = 0; r < EPT; ++r) {
        float a = Sin + (((r >> 2) & 1) ? be[9]  : al[9])
                      + (((r >> 1) & 1) ? be[10] : al[10])
                      + ((r & 1)        ? be[11] : al[11]);
        rot(vr[r], vi[r], a, 1.f);
    }

    // ---- BS1: bits 0-2 | 3-5 | 6-8 | 9-11 ----
    bfly3(vr, vi);
    exchange<0, 3, false>(B1, vr, vi, t); bfly3(vr, vi);
    exchange<3, 6, false>(B1, vr, vi, t); bfly3(vr, vi);
    exchange<6, 9, true >(B1, vr, vi, t); bfly3(vr, vi);

    // ---- D_theta at p9 (j = r*512 + t): qubits 0,1,2 <-> r bits 2,1,0; 1/64 folds BS1 scale ----
    #pragma unroll
    for (int r = 0; r < EPT; ++r) {
        float a = Sth + (((r >> 2) & 1) ? 0.f : th[0])
                      + (((r >> 1) & 1) ? 0.f : th[1])
                      + ((r & 1)        ? 0.f : th[2]);
        rot(vr[r], vi[r], a, 1.0f / 64.0f);
    }

    // ---- BS2: bits 9-11 | 6-8 | 3-5 | 0-2 (down-ladder, 3 exchanges) ----
    bfly3(vr, vi);
    exchange<9, 6, true >(B2, vr, vi, t); bfly3(vr, vi);
    exchange<6, 3, false>(B1, vr, vi, t); bfly3(vr, vi);
    exchange<3, 0, false>(B1, vr, vi, t); bfly3(vr, vi);

    // ---- D_phi at p0 + store (1/64 folds BS2 scale) ----
    float* outr = out + (size_t)b * 2 * NN;
    float* outi = outr + NN;
    #pragma unroll
    for (int r = 0; r < EPT; ++r) {
        float a = Sph + (((r >> 2) & 1) ? 0.f : ph[9])
                      + (((r >> 1) & 1) ? 0.f : ph[10])
                      + ((r & 1)        ? 0.f : ph[11]);
        rot(vr[r], vi[r], a, 1.0f / 64.0f);
    }
    {
        float4 o0 = make_float4(vr[0], vr[1], vr[2], vr[3]);
        float4 o1 = make_float4(vr[4], vr[5], vr[6], vr[7]);
        float4 o2 = make_float4(vi[0], vi[1], vi[2], vi[3]);
        float4 o3 = make_float4(vi[4], vi[5], vi[6], vi[7]);
        ((float4*)(outr + t * EPT))[0] = o0;
        ((float4*)(outr + t * EPT))[1] = o1;
        ((float4*)(outi + t * EPT))[0] = o2;
        ((float4*)(outi + t * EPT))[1] = o3;
    }
}

extern "C" void kernel_launch(void* const* d_in, const int* in_sizes, int n_in,
                              void* d_out, int out_size, void* d_ws, size_t ws_size,
                              hipStream_t stream) {
    const float* x      = (const float*)d_in[0];
    const float* alphas = (const float*)d_in[1];
    const float* betas  = (const float*)d_in[2];
    const float* thetas = (const float*)d_in[3];
    const float* phis   = (const float*)d_in[4];
    float* out = (float*)d_out;

    const int batch = in_sizes[0] / (2 * NN);   // 64
    qubit_layer_kernel<<<batch, BLK, 0, stream>>>(x, alphas, betas, thetas, phis, out);
}

// Round 6
// 10.259 us; speedup vs baseline: 2.5675x; 1.4987x over previous
//
#include <hip/hip_runtime.h>
#include <math.h>

#define NN 4096
#define BLK 512
#define EPT 8
#define PADSZ (NN + (NN >> 3))   // padded idx jj = j + (j>>3): 4-way b64 everywhere (floor)

__device__ __forceinline__ void cmul(float& ar, float& ai, float br, float bi) {
    float nr = ar * br - ai * bi;
    float ni = ar * bi + ai * br;
    ar = nr; ai = ni;
}

// new_u = u + i*w ; new_w = w + i*u  (1/sqrt2 folded into theta/phi tables)
__device__ __forceinline__ void bfly_pair(float* vr, float* vi, int a, int b) {
    float ur = vr[a], ui = vi[a], wr = vr[b], wi = vi[b];
    vr[a] = ur - wi; vi[a] = ui + wr;
    vr[b] = wr - ui; vi[b] = wi + ur;
}

__device__ __forceinline__ void bfly3(float* vr, float* vi) {
    bfly_pair(vr, vi, 0, 1); bfly_pair(vr, vi, 2, 3); bfly_pair(vr, vi, 4, 5); bfly_pair(vr, vi, 6, 7);
    bfly_pair(vr, vi, 0, 2); bfly_pair(vr, vi, 1, 3); bfly_pair(vr, vi, 4, 6); bfly_pair(vr, vi, 5, 7);
    bfly_pair(vr, vi, 0, 4); bfly_pair(vr, vi, 1, 5); bfly_pair(vr, vi, 2, 6); bfly_pair(vr, vi, 3, 7);
}

template<int P>
__device__ __forceinline__ int jidx(int t, int r) {
    return ((t >> P) << (P + 3)) | (r << P) | (t & ((1 << P) - 1));
}

// Exchange register-bit block PC -> PN through LDS.
// CROSS=false: wave-owner bits (j[11:9] = t[8:6]) preserved -> wave-private slice;
// per-wave DS ordering makes it safe with just a compiler fence.
template<int PC, int PN, bool CROSS>
__device__ __forceinline__ void exchange(float2* buf, float* vr, float* vi, int t) {
    #pragma unroll
    for (int r = 0; r < EPT; ++r) {
        int j = jidx<PC>(t, r);
        buf[j + (j >> 3)] = make_float2(vr[r], vi[r]);
    }
    if (CROSS) { __syncthreads(); }
    else       { asm volatile("" ::: "memory"); }
    #pragma unroll
    for (int r = 0; r < EPT; ++r) {
        int j = jidx<PN>(t, r);
        float2 v = buf[j + (j >> 3)];
        vr[r] = v.x; vi[r] = v.y;
    }
}

__global__ __launch_bounds__(BLK) void qubit_layer_kernel(
    const float* __restrict__ x,
    const float* __restrict__ alphas, const float* __restrict__ betas,
    const float* __restrict__ thetas, const float* __restrict__ phis,
    float* __restrict__ out)
{
    __shared__ float2 B1[PADSZ];
    __shared__ float2 B2[PADSZ];
    __shared__ float2 tbl[6][64];   // 0=in_lo 1=in_hi 2=th_lo(/64) 3=th_hi 4=ph_lo(/64) 5=ph_hi

    const int t = threadIdx.x;
    const int b = blockIdx.x;

    // ---- build phase tables (1 sincos per builder thread; verified in R2) ----
    if (t < 384) {
        int part = t >> 6, idx = t & 63, set = part >> 1, half = part & 1;
        float a = 0.f;
        #pragma unroll
        for (int m = 0; m < 6; ++m) {
            int q = half ? m : (6 + m);
            int bit = (idx >> (5 - m)) & 1;
            float av, bv;
            if (set == 0)      { av = alphas[q]; bv = betas[q]; }
            else if (set == 1) { av = thetas[q]; bv = 0.f; }
            else               { av = phis[q];   bv = 0.f; }
            a += bit ? bv : av;
        }
        float s, c;
        __sincosf(a, &s, &c);
        float sc = (set >= 1 && half == 0) ? (1.0f / 64.0f) : 1.0f;
        tbl[part][idx] = make_float2(c * sc, s * sc);
    }

    // ---- load at p0 layout: j = t*8 + r ----
    const float* xr = x + (size_t)b * 2 * NN;
    const float* xi = xr + NN;
    float vr[EPT], vi[EPT];
    {
        float4 a0 = ((const float4*)(xr + t * EPT))[0];
        float4 a1 = ((const float4*)(xr + t * EPT))[1];
        float4 c0 = ((const float4*)(xi + t * EPT))[0];
        float4 c1 = ((const float4*)(xi + t * EPT))[1];
        vr[0]=a0.x; vr[1]=a0.y; vr[2]=a0.z; vr[3]=a0.w; vr[4]=a1.x; vr[5]=a1.y; vr[6]=a1.z; vr[7]=a1.w;
        vi[0]=c0.x; vi[1]=c0.y; vi[2]=c0.z; vi[3]=c0.w; vi[4]=c1.x; vi[5]=c1.y; vi[6]=c1.z; vi[7]=c1.w;
    }
    __syncthreads();   // tables ready

    // ---- D_in at p0: l = (t&7)*8 + r (b128 vector reads), h = t>>3 (broadcast) ----
    {
        float2 eh = tbl[1][t >> 3];
        const float4* elv = (const float4*)&tbl[0][(t & 7) << 3];
        #pragma unroll
        for (int k = 0; k < 4; ++k) {
            float4 e2 = elv[k];
            float er0 = e2.x, ei0 = e2.y, er1 = e2.z, ei1 = e2.w;
            cmul(er0, ei0, eh.x, eh.y);
            cmul(er1, ei1, eh.x, eh.y);
            cmul(vr[2*k],   vi[2*k],   er0, ei0);
            cmul(vr[2*k+1], vi[2*k+1], er1, ei1);
        }
    }

    // ---- BS1: bits 0-2 | 3-5 | 6-8 | 9-11 ----
    bfly3(vr, vi);
    exchange<0, 3, false>(B1, vr, vi, t); bfly3(vr, vi);
    exchange<3, 6, false>(B1, vr, vi, t); bfly3(vr, vi);
    exchange<6, 9, true >(B1, vr, vi, t); bfly3(vr, vi);

    // ---- D_theta at p9 (j = r*512 + t): l = t&63 (broadcast), h = 8r + (t>>6) (broadcast) ----
    {
        float2 el = tbl[2][t & 63];
        #pragma unroll
        for (int r = 0; r < EPT; ++r) {
            float2 eh = tbl[3][(t >> 6) + (r << 3)];
            float er = el.x, ei = el.y;
            cmul(er, ei, eh.x, eh.y);
            cmul(vr[r], vi[r], er, ei);
        }
    }

    // ---- BS2 down-ladder: bits 9-11 | 6-8 | 3-5 | 0-2 ----
    bfly3(vr, vi);
    exchange<9, 6, true >(B2, vr, vi, t); bfly3(vr, vi);
    exchange<6, 3, false>(B1, vr, vi, t); bfly3(vr, vi);
    exchange<3, 0, false>(B1, vr, vi, t); bfly3(vr, vi);

    // ---- D_phi at p0 + float4 stores ----
    {
        float2 eh = tbl[5][t >> 3];
        const float4* elv = (const float4*)&tbl[4][(t & 7) << 3];
        #pragma unroll
        for (int k = 0; k < 4; ++k) {
            float4 e2 = elv[k];
            float er0 = e2.x, ei0 = e2.y, er1 = e2.z, ei1 = e2.w;
            cmul(er0, ei0, eh.x, eh.y);
            cmul(er1, ei1, eh.x, eh.y);
            cmul(vr[2*k],   vi[2*k],   er0, ei0);
            cmul(vr[2*k+1], vi[2*k+1], er1, ei1);
        }
    }
    float* outr = out + (size_t)b * 2 * NN;
    float* outi = outr + NN;
    {
        ((float4*)(outr + t * EPT))[0] = make_float4(vr[0], vr[1], vr[2], vr[3]);
        ((float4*)(outr + t * EPT))[1] = make_float4(vr[4], vr[5], vr[6], vr[7]);
        ((float4*)(outi + t * EPT))[0] = make_float4(vi[0], vi[1], vi[2], vi[3]);
        ((float4*)(outi + t * EPT))[1] = make_float4(vi[4], vi[5], vi[6], vi[7]);
    }
}

extern "C" void kernel_launch(void* const* d_in, const int* in_sizes, int n_in,
                              void* d_out, int out_size, void* d_ws, size_t ws_size,
                              hipStream_t stream) {
    const float* x      = (const float*)d_in[0];
    const float* alphas = (const float*)d_in[1];
    const float* betas  = (const float*)d_in[2];
    const float* thetas = (const float*)d_in[3];
    const float* phis   = (const float*)d_in[4];
    float* out = (float*)d_out;

    const int batch = in_sizes[0] / (2 * NN);   // 64
    qubit_layer_kernel<<<batch, BLK, 0, stream>>>(x, alphas, betas, thetas, phis, out);
}